// Round 4
// baseline (391.538 us; speedup 1.0000x reference)
//
#include <hip/hip_runtime.h>
#include <stdint.h>

#define DIM 128
#define NPROJ 256
#define TPB 64                     // tokens per block (4 waves x 16)
#define TAU 0.016f                 // refine threshold on |k_proj_f16| (~7 sigma of f16 dot err)
#define QCAP 512
#define DEQ 0.004895758348888673f  // sqrt(pi/2)/256

typedef _Float16 f16x8 __attribute__((ext_vector_type(8)));
typedef float f32x4 __attribute__((ext_vector_type(4)));

// ---- prep: S fp32 -> f16 B-fragments, pre-swizzled into MFMA lane order ----
// frag fid = c*8 + ks*2 + f; lane l holds B[n=p][k=d]: p = c*32 + f*16 + (l&15),
// d = ks*32 + (l>>4)*8 + j
__global__ __launch_bounds__(256) void qjl_prep(const float* __restrict__ Sg,
                                                _Float16* __restrict__ ws) {
    int t = blockIdx.x * 256 + threadIdx.x;   // 0..4095
    int lane = t & 63, fid = t >> 6;          // 64 frags
    int f = fid & 1, ks = (fid >> 1) & 3, c = fid >> 3;
    int p = c * 32 + f * 16 + (lane & 15);
    int d0 = ks * 32 + (lane >> 4) * 8;
    const float4* s4 = (const float4*)(Sg + p * DIM + d0);
    float4 a = s4[0], b = s4[1];
    f16x8 h = {(_Float16)a.x, (_Float16)a.y, (_Float16)a.z, (_Float16)a.w,
               (_Float16)b.x, (_Float16)b.y, (_Float16)b.z, (_Float16)b.w};
    *(f16x8*)(ws + (size_t)fid * 512 + lane * 8) = h;
}

// load the 4 B-frags of (chunk C, 16-proj tile T) into named buffer
#define LOADT(buf, C, T)                                                             \
    { _Pragma("unroll")                                                              \
      for (int ks = 0; ks < 4; ++ks)                                                 \
          buf[ks] = *(const f16x8*)(ws + (size_t)((C) * 8 + ks * 2 + (T)) * 512 + lane * 8); }

// A fragments (16 K or Q rows per wave) fp32 -> f16 into dst[4]
#define LOADA(dst, src)                                                              \
    { const float* rp = (src) + (tok0 + wv * 16 + m) * DIM;                          \
      _Pragma("unroll")                                                              \
      for (int ks = 0; ks < 4; ++ks) {                                               \
          int d0 = ks * 32 + quad * 8;                                               \
          float4 x = *(const float4*)(rp + d0);                                      \
          float4 y = *(const float4*)(rp + d0 + 4);                                  \
          dst[ks] = (f16x8){(_Float16)x.x, (_Float16)x.y, (_Float16)x.z, (_Float16)x.w, \
                            (_Float16)y.x, (_Float16)y.y, (_Float16)y.z, (_Float16)y.w}; } }

// Fused step: k_proj and q_proj on the same B tile; est += sign(k)*q directly.
// Near-zero k_proj -> candidate queue (stores the f16 sign actually applied).
#define F_STEP(C, T, buf)                                                            \
    { f32x4 k0 = {0,0,0,0}, q0 = {0,0,0,0};                                          \
      _Pragma("unroll")                                                              \
      for (int ks = 0; ks < 4; ++ks) {                                               \
          k0 = __builtin_amdgcn_mfma_f32_16x16x32_f16(ak[ks], buf[ks], k0, 0,0,0);   \
          q0 = __builtin_amdgcn_mfma_f32_16x16x32_f16(aq[ks], buf[ks], q0, 0,0,0);   \
      }                                                                              \
      _Pragma("unroll")                                                              \
      for (int r = 0; r < 4; ++r) {                                                  \
          uint32_t s0 = __float_as_uint(k0[r]) & 0x80000000u;                        \
          est[r] += __uint_as_float(__float_as_uint(q0[r]) ^ s0);                    \
          if (__builtin_expect(fabsf(k0[r]) < TAU, 0)) {                             \
              int idx = atomicAdd(&qn, 1);                                           \
              if (idx < QCAP) qmeta[idx] = (uint32_t)(wv * 16 + quad * 4 + r)        \
                  | ((uint32_t)((C) * 32 + (T) * 16 + m) << 8)                       \
                  | ((s0 ? 0u : 1u) << 16);                                          \
          } } }

// 16 tokens/wave: live set ~95-100 VGPRs (ak[4]+aq[4]=32, tA+tB=32, acc+est+addr).
// Rounds 1/3 proved the allocator will not grant >128 regs regardless of
// attributes (it allocated 84 then 128 and spilled ~170-530 MB of scratch).
// So fit under 128 structurally, and pin 4 waves/EU (=128-reg budget) exactly.
__global__
__attribute__((amdgpu_flat_work_group_size(256, 256), amdgpu_waves_per_eu(4, 4)))
void qjl_main(
    const float* __restrict__ qg, const float* __restrict__ kg,
    const float* __restrict__ Sg, const _Float16* __restrict__ ws,
    float* __restrict__ out)
{
    __shared__ float    est_s[TPB];
    __shared__ uint32_t qmeta[QCAP];
    __shared__ int      qn;

    const int tid = threadIdx.x, lane = tid & 63, wv = tid >> 6;
    const int m = lane & 15, quad = lane >> 4;
    const long tok0 = (long)blockIdx.x * TPB;
    if (tid == 0) qn = 0;
    __syncthreads();

    f16x8 ak[4], aq[4];        // A fragments: 16 K rows + 16 Q rows
    f16x8 tA[4], tB[4];        // B half-chunk double buffer
    float est[4] = {0.f, 0.f, 0.f, 0.f};

    // ================= single fused pass =================
    // HBM loads (high latency) issued first, then the L2-resident B tiles.
    LOADA(ak, kg);
    LOADA(aq, qg);
    LOADT(tA, 0, 0);
    LOADT(tB, 0, 1);
    F_STEP(0, 0, tA); LOADT(tA, 1, 0);
    F_STEP(0, 1, tB); LOADT(tB, 1, 1);
    F_STEP(1, 0, tA); LOADT(tA, 2, 0);
    F_STEP(1, 1, tB); LOADT(tB, 2, 1);
    F_STEP(2, 0, tA); LOADT(tA, 3, 0);
    F_STEP(2, 1, tB); LOADT(tB, 3, 1);
    F_STEP(3, 0, tA); LOADT(tA, 4, 0);
    F_STEP(3, 1, tB); LOADT(tB, 4, 1);
    F_STEP(4, 0, tA); LOADT(tA, 5, 0);
    F_STEP(4, 1, tB); LOADT(tB, 5, 1);
    F_STEP(5, 0, tA); LOADT(tA, 6, 0);
    F_STEP(5, 1, tB); LOADT(tB, 6, 1);
    F_STEP(6, 0, tA); LOADT(tA, 7, 0);
    F_STEP(6, 1, tB); LOADT(tB, 7, 1);
    F_STEP(7, 0, tA);
    F_STEP(7, 1, tB);

    // ---- reduce est over the 16 proj-lanes ----
    #pragma unroll
    for (int r = 0; r < 4; ++r) {
        float e = est[r];
        e += __shfl_xor(e, 1);
        e += __shfl_xor(e, 2);
        e += __shfl_xor(e, 4);
        e += __shfl_xor(e, 8);
        if (m == 0) est_s[wv * 16 + quad * 4 + r] = DEQ * e;
    }
    __syncthreads();

    // ---- refine: per-thread exact fp64 dots; patch est on sign flips ----
    int nc = qn < QCAP ? qn : QCAP;
    for (int i = tid; i < nc; i += 256) {
        uint32_t mm = qmeta[i];
        int tl = mm & 255;
        int p  = (mm >> 8) & 255;
        int sf = (mm >> 16) & 1;
        const float4* kr = (const float4*)(kg + (tok0 + tl) * DIM);
        const float4* qr = (const float4*)(qg + (tok0 + tl) * DIM);
        const float4* sr = (const float4*)(Sg + (long)p * DIM);
        double dk = 0.0, dq = 0.0;
        #pragma unroll 8
        for (int j = 0; j < 32; ++j) {
            float4 kv4 = kr[j], qv4 = qr[j], sv4 = sr[j];
            dk += (double)kv4.x * (double)sv4.x + (double)kv4.y * (double)sv4.y
                + (double)kv4.z * (double)sv4.z + (double)kv4.w * (double)sv4.w;
            dq += (double)qv4.x * (double)sv4.x + (double)qv4.y * (double)sv4.y
                + (double)qv4.z * (double)sv4.z + (double)qv4.w * (double)sv4.w;
        }
        int st = (dk > 0.0) ? 1 : 0;
        if (st != sf) {
            float sg = sf ? 1.f : -1.f;
            atomicAdd(&est_s[tl], -2.f * DEQ * (float)dq * sg);
        }
    }
    __syncthreads();

    if (tid < TPB) out[tok0 + tid] = est_s[tid];
}

extern "C" void kernel_launch(void* const* d_in, const int* in_sizes, int n_in,
                              void* d_out, int out_size, void* d_ws, size_t ws_size,
                              hipStream_t stream) {
    const float* q = (const float*)d_in[0];
    const float* k = (const float*)d_in[1];
    const float* S = (const float*)d_in[2];
    float* out = (float*)d_out;
    _Float16* ws = (_Float16*)d_ws;
    hipLaunchKernelGGL(qjl_prep, dim3(16), dim3(256), 0, stream, S, ws);
    int nblocks = out_size / TPB;   // 262144 / 64 = 4096
    hipLaunchKernelGGL(qjl_main, dim3(nblocks), dim3(256), 0, stream, q, k, S, ws, out);
}

// Round 5
// 313.552 us; speedup vs baseline: 1.2487x; 1.2487x over previous
//
#include <hip/hip_runtime.h>
#include <stdint.h>

#define DIM 128
#define NPROJ 256
#define TPB 64                     // tokens per block (4 waves x 16)
#define TAU 0.016f                 // refine threshold on |k_proj_f16| (~7 sigma of f16 dot err)
#define QCAP 512
#define DEQ 0.004895758348888673f  // sqrt(pi/2)/256

typedef _Float16 f16x8 __attribute__((ext_vector_type(8)));
typedef float f32x4 __attribute__((ext_vector_type(4)));

// ---- prep: S fp32 -> f16 B-fragments, pre-swizzled into MFMA lane order ----
// frag fid = c*8 + ks*2 + f; lane l holds B[n=p][k=d]: p = c*32 + f*16 + (l&15),
// d = ks*32 + (l>>4)*8 + j
__global__ __launch_bounds__(256) void qjl_prep(const float* __restrict__ Sg,
                                                _Float16* __restrict__ ws) {
    int t = blockIdx.x * 256 + threadIdx.x;   // 0..4095
    int lane = t & 63, fid = t >> 6;          // 64 frags
    int f = fid & 1, ks = (fid >> 1) & 3, c = fid >> 3;
    int p = c * 32 + f * 16 + (lane & 15);
    int d0 = ks * 32 + (lane >> 4) * 8;
    const float4* s4 = (const float4*)(Sg + p * DIM + d0);
    float4 a = s4[0], b = s4[1];
    f16x8 h = {(_Float16)a.x, (_Float16)a.y, (_Float16)a.z, (_Float16)a.w,
               (_Float16)b.x, (_Float16)b.y, (_Float16)b.z, (_Float16)b.w};
    *(f16x8*)(ws + (size_t)fid * 512 + lane * 8) = h;
}

// load the 4 B-frags of (chunk C, 16-proj tile T) from LDS into named buffer
// contiguous lane*16B pattern -> conflict-free ds_read_b128
#define LOADT(buf, C, T)                                                             \
    { _Pragma("unroll")                                                              \
      for (int ks = 0; ks < 4; ++ks)                                                 \
          buf[ks] = *(const f16x8*)(bs + ((C) * 8 + ks * 2 + (T)) * 512 + lane * 8); }

// A fragments (16 K or Q rows per wave) fp32 -> f16 into dst[4]
#define LOADA(dst, src)                                                              \
    { const float* rp = (src) + (tok0 + wv * 16 + m) * DIM;                          \
      _Pragma("unroll")                                                              \
      for (int ks = 0; ks < 4; ++ks) {                                               \
          int d0 = ks * 32 + quad * 8;                                               \
          float4 x = *(const float4*)(rp + d0);                                      \
          float4 y = *(const float4*)(rp + d0 + 4);                                  \
          dst[ks] = (f16x8){(_Float16)x.x, (_Float16)x.y, (_Float16)x.z, (_Float16)x.w, \
                            (_Float16)y.x, (_Float16)y.y, (_Float16)y.z, (_Float16)y.w}; } }

// Fused step: k_proj and q_proj on the same B tile; est += sign(k)*q directly.
// Near-zero k_proj -> candidate queue (stores the f16 sign actually applied).
#define F_STEP(C, T, buf)                                                            \
    { f32x4 k0 = {0,0,0,0}, q0 = {0,0,0,0};                                          \
      _Pragma("unroll")                                                              \
      for (int ks = 0; ks < 4; ++ks) {                                               \
          k0 = __builtin_amdgcn_mfma_f32_16x16x32_f16(ak[ks], buf[ks], k0, 0,0,0);   \
          q0 = __builtin_amdgcn_mfma_f32_16x16x32_f16(aq[ks], buf[ks], q0, 0,0,0);   \
      }                                                                              \
      _Pragma("unroll")                                                              \
      for (int r = 0; r < 4; ++r) {                                                  \
          uint32_t s0 = __float_as_uint(k0[r]) & 0x80000000u;                        \
          est[r] += __uint_as_float(__float_as_uint(q0[r]) ^ s0);                    \
          if (__builtin_expect(fabsf(k0[r]) < TAU, 0)) {                             \
              int idx = atomicAdd(&qn, 1);                                           \
              if (idx < QCAP) qmeta[idx] = (uint32_t)(wv * 16 + quad * 4 + r)        \
                  | ((uint32_t)((C) * 32 + (T) * 16 + m) << 8)                       \
                  | ((s0 ? 0u : 1u) << 16);                                          \
          } } }

// B-fragments (64 KB, entire S in f16) live in LDS, staged once per block via
// async global_load_lds (no VGPR round-trip). Live register set is now only
// ak[4]+aq[4]+tA+tB+temps ~100 VGPRs: rounds 1/3/4 proved that keeping the
// B-stream in registers makes the allocator spill (84/128/64 VGPRs granted,
// 170-530 MB scratch traffic). launch_bounds(256,2) = round 0's proven
// no-spill configuration; LDS (66 KB) caps residency at 2 blocks/CU anyway.
__global__ __launch_bounds__(256, 2) void qjl_main(
    const float* __restrict__ qg, const float* __restrict__ kg,
    const float* __restrict__ Sg, const _Float16* __restrict__ ws,
    float* __restrict__ out)
{
    __shared__ _Float16 bs[32768];   // 64 KB: all 64 B-fragments
    __shared__ float    est_s[TPB];
    __shared__ uint32_t qmeta[QCAP];
    __shared__ int      qn;

    const int tid = threadIdx.x, lane = tid & 63, wv = tid >> 6;
    const int m = lane & 15, quad = lane >> 4;
    const long tok0 = (long)blockIdx.x * TPB;
    if (tid == 0) qn = 0;

    // ---- async stage: ws (64 KB, L2-resident) -> LDS, 16B per lane per call ----
    {
        const char* gsrc = (const char*)ws + tid * 16;
        char* ldst = (char*)bs + tid * 16;
        #pragma unroll
        for (int r = 0; r < 16; ++r)
            __builtin_amdgcn_global_load_lds(
                (const __attribute__((address_space(1))) void*)(gsrc + r * 4096),
                (__attribute__((address_space(3))) void*)(ldst + r * 4096),
                16, 0, 0);
    }

    f16x8 ak[4], aq[4];        // A fragments: 16 K rows + 16 Q rows
    f16x8 tA[4], tB[4];        // B tile double buffer (fed from LDS)
    float est[4] = {0.f, 0.f, 0.f, 0.f};

    // A loads (HBM, long latency) issued while the LDS copy is in flight.
    LOADA(ak, kg);
    LOADA(aq, qg);
    __syncthreads();           // drains vmcnt: LDS copy + A loads complete

    // ================= single fused pass over 16 B tiles =================
    LOADT(tA, 0, 0);
    LOADT(tB, 0, 1);
    F_STEP(0, 0, tA); LOADT(tA, 1, 0);
    F_STEP(0, 1, tB); LOADT(tB, 1, 1);
    F_STEP(1, 0, tA); LOADT(tA, 2, 0);
    F_STEP(1, 1, tB); LOADT(tB, 2, 1);
    F_STEP(2, 0, tA); LOADT(tA, 3, 0);
    F_STEP(2, 1, tB); LOADT(tB, 3, 1);
    F_STEP(3, 0, tA); LOADT(tA, 4, 0);
    F_STEP(3, 1, tB); LOADT(tB, 4, 1);
    F_STEP(4, 0, tA); LOADT(tA, 5, 0);
    F_STEP(4, 1, tB); LOADT(tB, 5, 1);
    F_STEP(5, 0, tA); LOADT(tA, 6, 0);
    F_STEP(5, 1, tB); LOADT(tB, 6, 1);
    F_STEP(6, 0, tA); LOADT(tA, 7, 0);
    F_STEP(6, 1, tB); LOADT(tB, 7, 1);
    F_STEP(7, 0, tA);
    F_STEP(7, 1, tB);

    // ---- reduce est over the 16 proj-lanes ----
    #pragma unroll
    for (int r = 0; r < 4; ++r) {
        float e = est[r];
        e += __shfl_xor(e, 1);
        e += __shfl_xor(e, 2);
        e += __shfl_xor(e, 4);
        e += __shfl_xor(e, 8);
        if (m == 0) est_s[wv * 16 + quad * 4 + r] = DEQ * e;
    }
    __syncthreads();

    // ---- refine: per-thread exact fp64 dots; patch est on sign flips ----
    int nc = qn < QCAP ? qn : QCAP;
    for (int i = tid; i < nc; i += 256) {
        uint32_t mm = qmeta[i];
        int tl = mm & 255;
        int p  = (mm >> 8) & 255;
        int sf = (mm >> 16) & 1;
        const float4* kr = (const float4*)(kg + (tok0 + tl) * DIM);
        const float4* qr = (const float4*)(qg + (tok0 + tl) * DIM);
        const float4* sr = (const float4*)(Sg + (long)p * DIM);
        double dk = 0.0, dq = 0.0;
        #pragma unroll 8
        for (int j = 0; j < 32; ++j) {
            float4 kv4 = kr[j], qv4 = qr[j], sv4 = sr[j];
            dk += (double)kv4.x * (double)sv4.x + (double)kv4.y * (double)sv4.y
                + (double)kv4.z * (double)sv4.z + (double)kv4.w * (double)sv4.w;
            dq += (double)qv4.x * (double)sv4.x + (double)qv4.y * (double)sv4.y
                + (double)qv4.z * (double)sv4.z + (double)qv4.w * (double)sv4.w;
        }
        int st = (dk > 0.0) ? 1 : 0;
        if (st != sf) {
            float sg = sf ? 1.f : -1.f;
            atomicAdd(&est_s[tl], -2.f * DEQ * (float)dq * sg);
        }
    }
    __syncthreads();

    if (tid < TPB) out[tok0 + tid] = est_s[tid];
}

extern "C" void kernel_launch(void* const* d_in, const int* in_sizes, int n_in,
                              void* d_out, int out_size, void* d_ws, size_t ws_size,
                              hipStream_t stream) {
    const float* q = (const float*)d_in[0];
    const float* k = (const float*)d_in[1];
    const float* S = (const float*)d_in[2];
    float* out = (float*)d_out;
    _Float16* ws = (_Float16*)d_ws;
    hipLaunchKernelGGL(qjl_prep, dim3(16), dim3(256), 0, stream, S, ws);
    int nblocks = out_size / TPB;   // 262144 / 64 = 4096
    hipLaunchKernelGGL(qjl_main, dim3(nblocks), dim3(256), 0, stream, q, k, S, ws, out);
}